// Round 7
// baseline (60.844 us; speedup 1.0000x reference)
//
#include <hip/hip_runtime.h>
#include <hip/hip_bf16.h>

// x[4096,2048] f32, w[2048,2048] f32, bias[2048] f32, indices = permutation of
// K axis applied to BOTH operands -> cancels out of the einsum; unused.
#define M_DIM 4096
#define N_DIM 2048
#define K_DIM 2048
#define K32   (K_DIM / 32)   // 64 k-chunks per 16-row block

// All-register GEMM: NO LDS, NO barriers. cvt emits operands in a
// fragment-chunked layout; GEMM loads fragments straight to VGPRs.
// chunk (rb, kb) = 1 KiB: elem(l, j): row = rb*16 + (l&15),
// k = kb*32 + (l>>4)*8 + j  -> exactly the mfma_16x16x32 operand layout.
// Block 128x128, 4 waves (2x2) of 64x64. Grid 512 = 2 blocks/CU.

typedef __bf16 bf16x8 __attribute__((ext_vector_type(8)));
typedef float f32x4 __attribute__((ext_vector_type(4)));
typedef unsigned short u16x8 __attribute__((ext_vector_type(8)));

__device__ __forceinline__ unsigned short f32_to_bf16_rne(float f) {
  unsigned int u = __float_as_uint(f);
  u += 0x7fffu + ((u >> 16) & 1u);
  return (unsigned short)(u >> 16);
}

// ---- f32 -> bf16 conversion into chunked fragment layout ----
// slot s (8 elems): chunk = s>>6, l = s&63; rb = chunk>>6, kb = chunk&63
// (K32 == 64). Writes coalesced; reads are 16 rows x 128B full lines.
__global__ __launch_bounds__(256) void cvt_chunk(
    const float* __restrict__ x, const float* __restrict__ w,
    unsigned short* __restrict__ outx, unsigned short* __restrict__ outw,
    int xslots, int totslots) {
  int s = blockIdx.x * 256 + threadIdx.x;
  if (s >= totslots) return;
  const float* in;
  unsigned short* out;
  int ls = s;
  if (s < xslots) { in = x; out = outx; }
  else            { in = w; out = outw; ls = s - xslots; }
  const int chunk = ls >> 6, l = ls & 63;
  const int rb = chunk >> 6, kb = chunk & 63;
  const size_t off = (size_t)(rb * 16 + (l & 15)) * K_DIM + kb * 32 + (l >> 4) * 8;
  f32x4 a = *reinterpret_cast<const f32x4*>(in + off);
  f32x4 b = *reinterpret_cast<const f32x4*>(in + off + 4);
  u16x8 o;
  o[0] = f32_to_bf16_rne(a[0]); o[1] = f32_to_bf16_rne(a[1]);
  o[2] = f32_to_bf16_rne(a[2]); o[3] = f32_to_bf16_rne(a[3]);
  o[4] = f32_to_bf16_rne(b[0]); o[5] = f32_to_bf16_rne(b[1]);
  o[6] = f32_to_bf16_rne(b[2]); o[7] = f32_to_bf16_rne(b[3]);
  reinterpret_cast<u16x8*>(out)[ls] = o;
}

#define LD8(p) (*reinterpret_cast<const bf16x8*>(p))

__global__ __launch_bounds__(256, 2) void gemm_reg(
    const unsigned short* __restrict__ Ac,  // chunked [M/16][K32][512]
    const unsigned short* __restrict__ Bc,  // chunked [N/16][K32][512]
    const float* __restrict__ bias,         // [N]
    float* __restrict__ C) {                // [M][N] f32
  const int tid  = threadIdx.x;
  const int lane = tid & 63;
  const int wave = tid >> 6;   // 0..3
  const int wr   = wave >> 1;  // 0..1
  const int wc   = wave & 1;   // 0..1

  // XCD swizzle: 8 XCDs x 64 consecutive wgids; wgid = bn*32 + bm so each
  // XCD works 2 bn-columns (W-panel 2 x 512 KB stays L2-resident) x all bm.
  const int orig = blockIdx.x;             // 0..511
  const int wgid = (orig & 7) * 64 + (orig >> 3);
  const int bn = wgid >> 5;                // 0..15
  const int bm = wgid & 31;                // 0..31

  // rolling fragment pointers; each LOADSET consumes 2 k-chunks (K=64).
  const unsigned short* pa[4];
  const unsigned short* pb[4];
#pragma unroll
  for (int mi = 0; mi < 4; ++mi)
    pa[mi] = Ac + (size_t)(bm * 8 + wr * 4 + mi) * K32 * 512 + lane * 8;
#pragma unroll
  for (int ni = 0; ni < 4; ++ni)
    pb[ni] = Bc + (size_t)(bn * 8 + wc * 4 + ni) * K32 * 512 + lane * 8;

  const f32x4 z = {0.f, 0.f, 0.f, 0.f};
  f32x4 acc[4][4];
#pragma unroll
  for (int i = 0; i < 4; ++i)
#pragma unroll
    for (int j = 0; j < 4; ++j) acc[i][j] = z;

  bf16x8 aX[4][2], bX[4][2], aY[4][2], bY[4][2];

#define LOADSET(aS, bS) do { \
    _Pragma("unroll") \
    for (int mi = 0; mi < 4; ++mi) { \
      aS[mi][0] = LD8(pa[mi]); aS[mi][1] = LD8(pa[mi] + 512); pa[mi] += 1024; \
    } \
    _Pragma("unroll") \
    for (int ni = 0; ni < 4; ++ni) { \
      bS[ni][0] = LD8(pb[ni]); bS[ni][1] = LD8(pb[ni] + 512); pb[ni] += 1024; \
    } \
  } while (0)

#define MFMASET(aS, bS) do { \
    _Pragma("unroll") \
    for (int kk = 0; kk < 2; ++kk) \
      _Pragma("unroll") \
      for (int mi = 0; mi < 4; ++mi) { \
        acc[mi][0] = __builtin_amdgcn_mfma_f32_16x16x32_bf16(aS[mi][kk], bS[0][kk], acc[mi][0], 0, 0, 0); \
        acc[mi][1] = __builtin_amdgcn_mfma_f32_16x16x32_bf16(aS[mi][kk], bS[1][kk], acc[mi][1], 0, 0, 0); \
        acc[mi][2] = __builtin_amdgcn_mfma_f32_16x16x32_bf16(aS[mi][kk], bS[2][kk], acc[mi][2], 0, 0, 0); \
        acc[mi][3] = __builtin_amdgcn_mfma_f32_16x16x32_bf16(aS[mi][kk], bS[3][kk], acc[mi][3], 0, 0, 0); \
      } \
  } while (0)

  // 32 K-tiles (K=64 each), double fragment-set, one-tile load-ahead.
  // No barriers, no sched pins -- the compiler interleaves loads into the
  // MFMA stream and emits counted vmcnt waits.
  LOADSET(aX, bX);                    // tile 0
#pragma unroll 1
  for (int p = 0; p < 15; ++p) {
    LOADSET(aY, bY);                  // tile 2p+1
    MFMASET(aX, bX);                  // tile 2p
    LOADSET(aX, bX);                  // tile 2p+2
    MFMASET(aY, bY);                  // tile 2p+1
  }
  LOADSET(aY, bY);                    // tile 31
  MFMASET(aX, bX);                    // tile 30
  MFMASET(aY, bY);                    // tile 31

  // ---- epilogue: C/D layout col = lane&15, row = (lane>>4)*4 + r ----
  const int fr = lane & 15;
  const int qq = lane >> 4;
  const int orow0 = bm * 128 + wr * 64 + qq * 4;
  const int ocol0 = bn * 128 + wc * 64 + fr;
#pragma unroll
  for (int ni = 0; ni < 4; ++ni) {
    const int col = ocol0 + ni * 16;
    const float bv = bias[col];
#pragma unroll
    for (int mi = 0; mi < 4; ++mi) {
      const int row = orow0 + mi * 16;
#pragma unroll
      for (int r = 0; r < 4; ++r)
        C[(size_t)(row + r) * N_DIM + col] = acc[mi][ni][r] + bv;
    }
  }
#undef MFMASET
#undef LOADSET
}

// ---- safety fallback ----
__global__ __launch_bounds__(256) void gemm_f32_naive(
    const float* __restrict__ X, const float* __restrict__ W,
    const float* __restrict__ bias, float* __restrict__ C) {
  int o = blockIdx.x * 256 + threadIdx.x;
  if (o >= M_DIM * N_DIM) return;
  int m = o / N_DIM, n = o % N_DIM;
  const float* xr = X + (size_t)m * K_DIM;
  const float* wr = W + (size_t)n * K_DIM;
  float s = 0.f;
  for (int k = 0; k < K_DIM; ++k) s += xr[k] * wr[k];
  C[o] = s + bias[n];
}

extern "C" void kernel_launch(void* const* d_in, const int* in_sizes, int n_in,
                              void* d_out, int out_size, void* d_ws, size_t ws_size,
                              hipStream_t stream) {
  const float* x    = (const float*)d_in[0];
  const float* w    = (const float*)d_in[1];
  const float* bias = (const float*)d_in[2];
  float* out = (float*)d_out;

  const size_t x_elems = (size_t)M_DIM * K_DIM;   // 8.39M
  const size_t w_elems = (size_t)N_DIM * K_DIM;   // 4.19M
  const size_t need = (x_elems + w_elems) * sizeof(unsigned short);

  if (ws_size < need) {
    gemm_f32_naive<<<(M_DIM * N_DIM + 255) / 256, 256, 0, stream>>>(x, w, bias, out);
    return;
  }

  unsigned short* xb = (unsigned short*)d_ws;
  unsigned short* wb = xb + x_elems;

  const int xslots = (int)(x_elems / 8);           // 1,048,576
  const int totslots = (int)((x_elems + w_elems) / 8);
  cvt_chunk<<<(totslots + 255) / 256, 256, 0, stream>>>(x, w, xb, wb, xslots, totslots);

  gemm_reg<<<512, 256, 0, stream>>>(xb, wb, bias, out);
}